// Round 1
// 271.639 us; speedup vs baseline: 1.0057x; 1.0057x over previous
//
#include <hip/hip_runtime.h>
#include <math.h>

// Problem constants (E zonotope rows, content = C*H*W)
#define EROWS 64
#define NCOL  8192                   // 8*32*32
#define TAIL_OFF (EROWS * NCOL)      // tail starts after head(1)+body(63) rows
#define TAIL_F4 (NCOL * NCOL / 4)    // tail size in float4 units (16,777,216)
#define ROW_F4  (NCOL / 4)           // float4 per row (2048)

// ws layout (bytes):
//   val     float[NCOL]  @ 0
//   flag    int[NCOL]    @ 32768
//   colof   int[NCOL]    @ 65536
//   tailval float[NCOL]  @ 98304
//   count   int          @ 131072
#define WS_VAL(ws)     ((float*)(ws))
#define WS_FLAG(ws)    ((int*)((char*)(ws) + 32768))
#define WS_COLOF(ws)   ((int*)((char*)(ws) + 65536))
#define WS_TAILVAL(ws) ((float*)((char*)(ws) + 98304))
#define WS_COUNT(ws)   ((int*)((char*)(ws) + 131072))

// Kernel 1: per-column err reduction -> head row + body rows + (val, flag).
// Math identical (same fp32 op order) to the verified kernel: absmax 0.
// 64-thread blocks -> 128 workgroups -> 128 CUs busy (was 32).
__global__ __launch_bounds__(64) void headbody_kernel(const float* __restrict__ x,
                                float* __restrict__ out,
                                float* __restrict__ val,
                                int* __restrict__ flag) {
    int k = blockIdx.x * 64 + threadIdx.x;   // exact: 128*64 == NCOL

    float err = 0.f;
#pragma unroll
    for (int e = 1; e < EROWS; ++e)          // 63 independent loads in flight
        err += fabsf(x[e * NCOL + k]);

    float x0    = x[k];
    float upper = x0 + err;
    float lower = x0 - err;

    float cross  = (lower * upper < 0.f) ? 1.f : 0.f;
    float nonneg = (lower >= 0.f) ? 1.f : 0.f;

    float lam = nonneg + cross * upper / (upper - lower);
    if (isnan(lam)) lam = 0.5f;

    float delta = fmaxf(-lam * lower, (1.f - lam) * upper);

    out[k] = (delta * 0.5f + lam * x0) * cross + x0 * nonneg;   // head

    float scale = lam * cross + nonneg;
    val[k]  = delta * 0.5f;
    flag[k] = (cross > 0.f) ? 1 : 0;

#pragma unroll
    for (int e = 1; e < EROWS; ++e)                             // body (x from L2)
        out[e * NCOL + k] = x[e * NCOL + k] * scale;
}

// Kernel 2: single-block compaction scan. Wave-level __shfl_up inclusive scan
// (no barriers within a wave) + one LDS combine across the 16 waves: 1 barrier
// total (was 20 with Hillis-Steele). Emits the inverse compaction map:
// colof[r] = column of the r-th crossing column, tailval[r] = val there.
__global__ __launch_bounds__(1024) void scan_kernel(const float* __restrict__ val,
                            const int* __restrict__ flag,
                            int* __restrict__ colof,
                            float* __restrict__ tailval,
                            int* __restrict__ count) {
    const int t    = threadIdx.x;        // 1024 threads, 16 waves
    const int lane = t & 63;
    const int wid  = t >> 6;

    // 8 consecutive flags per thread, vectorized loads.
    int4 a = ((const int4*)flag)[t * 2 + 0];
    int4 b = ((const int4*)flag)[t * 2 + 1];
    int f[8] = {a.x, a.y, a.z, a.w, b.x, b.y, b.z, b.w};

    int s = 0;
#pragma unroll
    for (int j = 0; j < 8; ++j) s += f[j];

    // Inclusive scan of per-thread sums within the 64-lane wave.
    int isc = s;
#pragma unroll
    for (int off = 1; off < 64; off <<= 1) {
        int v = __shfl_up(isc, off);
        if (lane >= off) isc += v;
    }

    __shared__ int wsum[16];
    if (lane == 63) wsum[wid] = isc;
    __syncthreads();

    int base = 0;
    for (int w = 0; w < wid; ++w) base += wsum[w];   // uniform per wave, <=15 LDS broadcasts

    int running = base + isc - s;                    // exclusive prefix for this thread
    const int kbase = t * 8;
#pragma unroll
    for (int j = 0; j < 8; ++j) {
        if (f[j]) {
            colof[running]   = kbase + j;
            tailval[running] = val[kbase + j];
            ++running;
        }
    }
    if (t == 1023) *count = base + isc;              // grand total
}

// Kernel 3: tail writer. Was 16.7M one-store threads (262K waves of ~6 insts:
// wave-churn bound, far below write BW). Now 2048 blocks x 256 threads
// (= 32 waves/CU exactly), each thread stores 32 float4 (512 B). Each block
// owns 4 rows; colof[row]/tailval[row] are block-uniform -> scalar loads.
__global__ __launch_bounds__(256) void tail_kernel(const int* __restrict__ colof,
                           const float* __restrict__ tailval,
                           const int* __restrict__ count,
                           float* __restrict__ out) {
    const int t    = threadIdx.x;
    const int row0 = blockIdx.x * 4;
    const int cnt  = *count;                         // uniform -> scalar
    float4* tail = (float4*)out + TAIL_OFF / 4;

#pragma unroll
    for (int j = 0; j < 4; ++j) {
        int   r   = row0 + j;
        // Guard: colof/tailval are garbage (poisoned ws) for r >= cnt.
        int   col = (r < cnt) ? colof[r]   : -1;
        float tv  = (r < cnt) ? tailval[r] : 0.f;
        float4* rowp = tail + (size_t)r * ROW_F4;
#pragma unroll
        for (int i = 0; i < 8; ++i) {
            int c0 = (t + i * 256) << 2;
            float4 v;
            v.x = (col == c0 + 0) ? tv : 0.f;
            v.y = (col == c0 + 1) ? tv : 0.f;
            v.z = (col == c0 + 2) ? tv : 0.f;
            v.w = (col == c0 + 3) ? tv : 0.f;
            rowp[t + i * 256] = v;                   // 1 KiB/wave contiguous
        }
    }
}

extern "C" void kernel_launch(void* const* d_in, const int* in_sizes, int n_in,
                              void* d_out, int out_size, void* d_ws, size_t ws_size,
                              hipStream_t stream) {
    const float* x = (const float*)d_in[0];
    float* out = (float*)d_out;

    headbody_kernel<<<NCOL / 64, 64, 0, stream>>>(x, out, WS_VAL(d_ws), WS_FLAG(d_ws));
    scan_kernel<<<1, 1024, 0, stream>>>(WS_VAL(d_ws), WS_FLAG(d_ws),
                                        WS_COLOF(d_ws), WS_TAILVAL(d_ws), WS_COUNT(d_ws));
    tail_kernel<<<NCOL / 4, 256, 0, stream>>>(WS_COLOF(d_ws), WS_TAILVAL(d_ws),
                                              WS_COUNT(d_ws), out);
}

// Round 5
// 271.541 us; speedup vs baseline: 1.0061x; 1.0004x over previous
//
#include <hip/hip_runtime.h>
#include <math.h>

// Problem constants (E zonotope rows, content = C*H*W)
#define EROWS 64
#define NCOL  8192                   // 8*32*32
#define TAIL_OFF (EROWS * NCOL)      // tail starts after head(1)+body(63) rows
#define TAIL_F4 (NCOL * NCOL / 4)    // tail size in float4 units (16,777,216)
#define FILL_BLOCKS 2048             // 2048 blocks x 256 thr x 32 f4 = whole tail
#define HB_BLOCKS   32               // 32 blocks x 256 thr = 8192 columns

// ws layout (bytes):
//   val     float[NCOL]  @ 0
//   flag    int[NCOL]    @ 32768
#define WS_VAL(ws)     ((float*)(ws))
#define WS_FLAG(ws)    ((int*)((char*)(ws) + 32768))

// POISON-SAFETY INVARIANT (learned the hard way, R2-R4 container faults):
// the harness can run kernels against poisoned ws (replay / re-poison paths).
// Therefore ws-derived data may be used in compares and value selects, and in
// CLAMPED address arithmetic only. Every store address below is provably
// in-bounds for arbitrary ws bit patterns.

// Kernel 1 (fused): blocks [0,2048) zero-fill the 256 MiB tail (pure float4
// stores, fixed addresses); blocks [2048,2080) do the per-column head/body
// math. The 2 MiB headbody read+compute overlaps the write stream instead of
// serializing behind it. Math is bit-identical (same fp32 op order) to the
// R1-verified kernel: absmax 0.
__global__ __launch_bounds__(256) void fused_kernel(const float* __restrict__ x,
                              float* __restrict__ out,
                              float* __restrict__ val,
                              int* __restrict__ flag) {
    const int t = threadIdx.x;

    if (blockIdx.x < FILL_BLOCKS) {
        // ---- tail zero-fill: each block writes 128 KiB contiguous ----
        float4* tail = (float4*)out + TAIL_OFF / 4;
        size_t base = (size_t)blockIdx.x * 8192;     // 32 f4/thread * 256 thr
        float4 z;  z.x = 0.f; z.y = 0.f; z.z = 0.f; z.w = 0.f;
#pragma unroll
        for (int i = 0; i < 32; ++i)
            tail[base + i * 256 + t] = z;            // 1 KiB/wave contiguous
        return;
    }

    // ---- head/body: one thread per column ----
    int k = (blockIdx.x - FILL_BLOCKS) * 256 + t;    // 32*256 == NCOL

    float err = 0.f;
#pragma unroll
    for (int e = 1; e < EROWS; ++e)                  // 63 independent loads
        err += fabsf(x[e * NCOL + k]);

    float x0    = x[k];
    float upper = x0 + err;
    float lower = x0 - err;

    float cross  = (lower * upper < 0.f) ? 1.f : 0.f;
    float nonneg = (lower >= 0.f) ? 1.f : 0.f;

    float lam = nonneg + cross * upper / (upper - lower);
    if (isnan(lam)) lam = 0.5f;

    float delta = fmaxf(-lam * lower, (1.f - lam) * upper);

    out[k] = (delta * 0.5f + lam * x0) * cross + x0 * nonneg;   // head

    float scale = lam * cross + nonneg;
    val[k]  = delta * 0.5f;
    flag[k] = (cross > 0.f) ? 1 : 0;

#pragma unroll
    for (int e = 1; e < EROWS; ++e)                  // body (x from L2)
        out[e * NCOL + k] = x[e * NCOL + k] * scale;
}

// Kernel 2: single-block compaction scan fused with the tail scatter.
// Wave-level __shfl_up inclusive scan (1 barrier total) -> exclusive prefix,
// then each crossing column k (the r-th in flat order) writes its value
// DIRECTLY into the zeroed tail: out[TAIL_OFF + r*NCOL + k] = val[k].
// The row index is CLAMPED to [0, NCOL-1] -- exact no-op for valid data
// (crossings <= NCOL so running <= 8191 at every taken write), but it makes
// the store address safe under poisoned-ws replay (the reference clips too:
// jnp.clip(rows, 0, n-1)). 8192 scattered 4-B stores (~512 KB): ~2 us.
__global__ __launch_bounds__(1024) void scan_kernel(const float* __restrict__ val,
                            const int* __restrict__ flag,
                            float* __restrict__ out) {
    const int t    = threadIdx.x;        // 1024 threads, 16 waves
    const int lane = t & 63;
    const int wid  = t >> 6;

    // 8 consecutive flags per thread, vectorized loads.
    int4 a = ((const int4*)flag)[t * 2 + 0];
    int4 b = ((const int4*)flag)[t * 2 + 1];
    int f[8] = {a.x, a.y, a.z, a.w, b.x, b.y, b.z, b.w};

    int s = 0;
#pragma unroll
    for (int j = 0; j < 8; ++j) s += f[j];

    // Inclusive scan of per-thread sums within the 64-lane wave.
    int isc = s;
#pragma unroll
    for (int off = 1; off < 64; off <<= 1) {
        int v = __shfl_up(isc, off);
        if (lane >= off) isc += v;
    }

    __shared__ int wsum[16];
    if (lane == 63) wsum[wid] = isc;
    __syncthreads();

    int base = 0;
    for (int w = 0; w < wid; ++w) base += wsum[w];   // uniform per wave

    int running = base + isc - s;                    // exclusive prefix
    const int kbase = t * 8;
    float* tail = out + TAIL_OFF;
#pragma unroll
    for (int j = 0; j < 8; ++j) {
        int k = kbase + j;
        if (f[j]) {
            // clamp: no-op on valid data, wild-write-proof under poison
            int r = running;
            r = (r < 0) ? 0 : r;
            r = (r > NCOL - 1) ? (NCOL - 1) : r;
            tail[(size_t)r * NCOL + k] = val[k];
            ++running;
        }
    }
}

extern "C" void kernel_launch(void* const* d_in, const int* in_sizes, int n_in,
                              void* d_out, int out_size, void* d_ws, size_t ws_size,
                              hipStream_t stream) {
    const float* x = (const float*)d_in[0];
    float* out = (float*)d_out;

    fused_kernel<<<FILL_BLOCKS + HB_BLOCKS, 256, 0, stream>>>(x, out, WS_VAL(d_ws), WS_FLAG(d_ws));
    scan_kernel<<<1, 1024, 0, stream>>>(WS_VAL(d_ws), WS_FLAG(d_ws), out);
}